// Round 3
// baseline (988.402 us; speedup 1.0000x reference)
//
#include <hip/hip_runtime.h>

typedef unsigned short u16t;
typedef unsigned int   u32t;
typedef __attribute__((ext_vector_type(8))) __bf16          bf16x8;
typedef __attribute__((ext_vector_type(8))) unsigned short  u16x8;
typedef __attribute__((ext_vector_type(4))) unsigned short  u16x4;
typedef __attribute__((ext_vector_type(4))) float           floatx4;

// f32 -> bf16 round-to-nearest-even (no NaN inputs in this problem)
__device__ __forceinline__ u16t f2b(float f){
  u32t u = __builtin_bit_cast(u32t, f);
  u += 0x7fffu + ((u >> 16) & 1u);
  return (u16t)(u >> 16);
}
__device__ __forceinline__ float b2f(u16t h){
  return __builtin_bit_cast(float, (u32t)h << 16);
}
// async global->LDS, 16B per lane. lds ptr must be wave-uniform (HW adds lane*16).
__device__ __forceinline__ void async16(const void* g, void* l){
  __builtin_amdgcn_global_load_lds((__attribute__((address_space(1))) void*)g,
                                   (__attribute__((address_space(3))) void*)l, 16, 0, 0);
}
__device__ __forceinline__ bf16x8 ldfrag(const u16t* p){
  return __builtin_bit_cast(bf16x8, *(const u16x8*)p);
}

// ---------------------------------------------------------------- cvt f32->bf16
__global__ __launch_bounds__(256)
void cvt_f32_bf16(const float* __restrict__ in, u16t* __restrict__ out, int n4){
  typedef __attribute__((ext_vector_type(4))) float f32x4;
  const f32x4* in4 = (const f32x4*)in;
  int stride = gridDim.x * blockDim.x;
  for (int i = blockIdx.x * blockDim.x + threadIdx.x; i < n4; i += stride){
    f32x4 v = in4[i];
    u16x4 o; o[0]=f2b(v[0]); o[1]=f2b(v[1]); o[2]=f2b(v[2]); o[3]=f2b(v[3]);
    *(u16x4*)(out + (size_t)i * 4) = o;
  }
}

// ---------------------------------------------------------------- GEMM C = A * B^T
// m97 structure. MFMA operands SWAPPED: acc holds D[n-quad][m-lane] so each lane
// owns 4 consecutive C-columns of one row -> vectorized epilogue stores.
template<int OUT_BF16>
__global__ __launch_bounds__(256)
void gemm_bt(const u16t* __restrict__ A, const u16t* __restrict__ B,
             void* __restrict__ Cv, int M, int N, int K)
{
  __shared__ u16t sA[128 * 32];
  __shared__ u16t sB[128 * 32];
  const int tid  = threadIdx.x;
  const int wave = tid >> 6, lane = tid & 63;
  const int lrow = lane & 15, quad = lane >> 4;
  const int m0 = blockIdx.y * 128, n0 = blockIdx.x * 128;
  const int wm = (wave >> 1) * 64, wn = (wave & 1) * 64;

  floatx4 acc[4][4] = {};

  const int byte0 = wave * 1024 + lane * 16;
  const int row0  = byte0 >> 6;
  const int kel0  = (byte0 & 63) >> 1;
  const int row1  = row0 + 64;

  char* lA0 = (char*)sA + wave * 1024;
  char* lA1 = (char*)sA + 4096 + wave * 1024;
  char* lB0 = (char*)sB + wave * 1024;
  char* lB1 = (char*)sB + 4096 + wave * 1024;

  const u16t* gA0 = A + (size_t)(m0 + row0) * K + kel0;
  const u16t* gA1 = A + (size_t)(m0 + row1) * K + kel0;
  const u16t* gB0 = B + (size_t)(n0 + row0) * K + kel0;
  const u16t* gB1 = B + (size_t)(n0 + row1) * K + kel0;

  for (int k0 = 0; k0 < K; k0 += 32){
    async16(gA0 + k0, lA0);
    async16(gA1 + k0, lA1);
    async16(gB0 + k0, lB0);
    async16(gB1 + k0, lB1);
    __syncthreads();
    bf16x8 a[4], b[4];
#pragma unroll
    for (int i = 0; i < 4; ++i) a[i] = ldfrag(&sA[(wm + i * 16 + lrow) * 32 + quad * 8]);
#pragma unroll
    for (int j = 0; j < 4; ++j) b[j] = ldfrag(&sB[(wn + j * 16 + lrow) * 32 + quad * 8]);
#pragma unroll
    for (int i = 0; i < 4; ++i)
#pragma unroll
      for (int j = 0; j < 4; ++j)
        acc[i][j] = __builtin_amdgcn_mfma_f32_16x16x32_bf16(b[j], a[i], acc[i][j], 0, 0, 0);
    __syncthreads();
  }

  // swapped C/D: lane = C-row (lrow), reg r = consecutive C-cols (quad*4+r)
#pragma unroll
  for (int i = 0; i < 4; ++i){
    const int row = m0 + wm + i * 16 + lrow;
#pragma unroll
    for (int j = 0; j < 4; ++j){
      const int col = n0 + wn + j * 16 + quad * 4;
      if (OUT_BF16){
        u16x4 ov;
#pragma unroll
        for (int r = 0; r < 4; ++r) ov[r] = f2b(acc[i][j][r]);
        *(u16x4*)((u16t*)Cv + (size_t)row * N + col) = ov;
      } else {
        *(floatx4*)((float*)Cv + (size_t)row * N + col) = acc[i][j];
      }
    }
  }
}

// ---------------------------------------------------------------- RoPE + layout
__global__ __launch_bounds__(256)
void rope_qk(const u16t* __restrict__ qkvb, const float* __restrict__ cosp,
             const float* __restrict__ sinp, u16t* __restrict__ qr, u16t* __restrict__ kr)
{
  const int row = blockIdx.x;            // b*2048 + t
  const int b = row >> 11, t = row & 2047;
  const u16t* src = qkvb + (size_t)row * 6144;
  for (int p = threadIdx.x; p < 2560; p += 256){
    u32t both = *(const u32t*)(src + 2 * p);
    float t0 = b2f((u16t)(both & 0xffff));
    float t1 = b2f((u16t)(both >> 16));
    int j = p & 63;
    float c = cosp[t * 64 + j], s = sinp[t * 64 + j];
    float o0 = t0 * c - t1 * s;
    float o1 = t0 * s + t1 * c;
    u32t packed = (u32t)f2b(o0) | ((u32t)f2b(o1) << 16);
    if (p < 2048){
      int h = p >> 6;
      *(u32t*)(qr + (((size_t)(b * 32 + h) * 2048 + t) * 128 + 2 * j)) = packed;
    } else {
      int kh = (p - 2048) >> 6;
      *(u32t*)(kr + (((size_t)(b * 8 + kh) * 2048 + t) * 128 + 2 * j)) = packed;
    }
  }
}

// ---------------------------------------------------------------- V transpose
__global__ __launch_bounds__(256)
void vtrans(const u16t* __restrict__ qkvb, u16t* __restrict__ vt)
{
  __shared__ u16t sV[64 * 128];
  const int tid = threadIdx.x;
  const int blk = blockIdx.x;                 // (b, kvh, tile)
  const int tile = blk & 31, kvh = (blk >> 5) & 7, b = blk >> 8;
  const int t0 = tile * 64;
  const size_t srcbase = (size_t)(b * 2048 + t0) * 6144 + 5120 + kvh * 128;
#pragma unroll
  for (int it = 0; it < 4; ++it){
    int task = it * 256 + tid;
    int rrow = task >> 4, cb = task & 15;
    *(u16x8*)&sV[rrow * 128 + cb * 8] =
        *(const u16x8*)(qkvb + srcbase + (size_t)rrow * 6144 + cb * 8);
  }
  __syncthreads();
  const size_t dstbase = (size_t)((b * 8 + kvh) * 128) * 2048 + t0;
#pragma unroll
  for (int it = 0; it < 4; ++it){
    int task = it * 256 + tid;
    int tc = task & 7, d = task >> 3;
    u16x8 v;
#pragma unroll
    for (int j = 0; j < 8; ++j) v[j] = sV[(tc * 8 + j) * 128 + d];
    *(u16x8*)(vt + dstbase + (size_t)d * 2048 + tc * 8) = v;
  }
}

// ---------------------------------------------------------------- flash attention v3
// Q-tile 128, K-tile 64. ALL MFMA operands swapped so lane = q-row:
//   S' = mfma(Kfrag, Qfrag): lane=q, regs=kv  -> softmax per-lane, 2 shuffles
//   O' = mfma(Vfrag, Pfrag): lane=q, regs=d   -> vectorized Y stores
// sP aliases sK with XOR-swizzled 16B chunks (row stride 64 u16 would conflict).
// LDS: sQ 32K | sK 16K | sV 16K = 64KB -> 2 blocks/CU.
__global__ __launch_bounds__(256)
void attn_fwd(const u16t* __restrict__ Qg, const u16t* __restrict__ Kg,
              const u16t* __restrict__ Vt, u16t* __restrict__ Y)
{
  __shared__ u16t smem[32768];         // 64 KB
  u16t* sQ = smem;                     // [dc:16][row:128] 16B chunks: u16 idx (dc*128+row)*8
  u16t* sK = smem + 16384;             // [dc:16][row:64]
  u16t* sV = smem + 24576;             // [kvc:8][d:128]
  u16t* sP = sK;                       // [q:128][kvchunk swizzled]: (q*8 + (c^(q&7)))*8

  const int tid  = threadIdx.x;
  const int wave = tid >> 6, lane = tid & 63;
  const int lrow = lane & 15, quad = lane >> 4;
  const int qt = 15 - (int)blockIdx.y;     // longest blocks dispatch first
  const int q0 = qt * 128;
  const int bh = blockIdx.x;
  const int b = bh >> 5, h = bh & 31, kvh = h >> 2;
  const float qscale = 0.088388347648318447f * 1.4426950408889634f; // 1/sqrt(128)*log2(e)

  // stage Q tile (32KB, 8 rounds)
  const size_t qbase = ((size_t)bh * 2048 + q0) * 128;
#pragma unroll
  for (int r = 0; r < 8; ++r){
    const int g  = r * 4 + wave;           // 64-chunk group id
    const int dc = g >> 1;
    const int row = ((g & 1) << 6) + lane;
    async16(Qg + qbase + (size_t)row * 128 + dc * 8, (char*)sQ + g * 1024);
  }

  float mi[2] = {-1e30f, -1e30f};
  float li[2] = {0.f, 0.f};
  floatx4 o[2][8] = {};
  const size_t kbase = ((size_t)(b * 8 + kvh) * 2048) * 128;
  const size_t vbase = ((size_t)(b * 8 + kvh) * 128) * 2048;
  const int qrow[2] = { q0 + wave * 32 + lrow, q0 + wave * 32 + 16 + lrow };
  const int ktiles = 2 * (qt + 1);

  for (int kt = 0; kt < ktiles; ++kt){
    const int k0 = kt * 64;
#pragma unroll
    for (int r = 0; r < 4; ++r){
      const int dc = r * 4 + wave;
      async16(Kg + kbase + (size_t)(k0 + lane) * 128 + dc * 8, (char*)sK + dc * 1024);
    }
#pragma unroll
    for (int r = 0; r < 4; ++r){
      const int kvc = r * 2 + (wave >> 1);
      const int dd  = (wave & 1) * 64 + lane;
      async16(Vt + vbase + (size_t)dd * 2048 + k0 + kvc * 8,
              (char*)sV + kvc * 2048 + (wave & 1) * 1024);
    }
    __syncthreads();   // K/V (and first-iter Q) ready

    // S' = K·Q^T : lane=q, (quad,reg)=kv.  s[mt][nt]: kv-tile nt, q-subtile mt
    floatx4 s[2][4] = {};
#pragma unroll
    for (int kk = 0; kk < 4; ++kk){
      bf16x8 yq0 = ldfrag(&sQ[((kk * 4 + quad) * 128 + wave * 32 + lrow) * 8]);
      bf16x8 yq1 = ldfrag(&sQ[((kk * 4 + quad) * 128 + wave * 32 + 16 + lrow) * 8]);
#pragma unroll
      for (int nt = 0; nt < 4; ++nt){
        bf16x8 xk = ldfrag(&sK[((kk * 4 + quad) * 64 + nt * 16 + lrow) * 8]);
        s[0][nt] = __builtin_amdgcn_mfma_f32_16x16x32_bf16(xk, yq0, s[0][nt], 0, 0, 0);
        s[1][nt] = __builtin_amdgcn_mfma_f32_16x16x32_bf16(xk, yq1, s[1][nt], 0, 0, 0);
      }
    }
    __syncthreads();   // all sK reads done before sP (alias) writes

    // scale + causal mask (only the last two k-tiles touch the diagonal)
    float tt[2][4][4];
    const bool do_mask = (kt >= 2 * qt);
#pragma unroll
    for (int mt = 0; mt < 2; ++mt)
#pragma unroll
      for (int nt = 0; nt < 4; ++nt)
#pragma unroll
        for (int r = 0; r < 4; ++r){
          float v = s[mt][nt][r] * qscale;
          if (do_mask && (k0 + nt * 16 + quad * 4 + r > qrow[mt])) v = -1e30f;
          tt[mt][nt][r] = v;
        }

    // online softmax: per-lane rows; reduce over quads (xor 16,32)
#pragma unroll
    for (int mt = 0; mt < 2; ++mt){
      float rmax = tt[mt][0][0];
#pragma unroll
      for (int nt = 0; nt < 4; ++nt)
#pragma unroll
        for (int r = 0; r < 4; ++r) rmax = fmaxf(rmax, tt[mt][nt][r]);
      rmax = fmaxf(rmax, __shfl_xor(rmax, 16, 64));
      rmax = fmaxf(rmax, __shfl_xor(rmax, 32, 64));
      float mn = fmaxf(mi[mt], rmax);
      float alpha = __builtin_amdgcn_exp2f(mi[mt] - mn);
      mi[mt] = mn;
      float lsum = 0.f;
      const int q = wave * 32 + mt * 16 + lrow;   // local q row
#pragma unroll
      for (int nt = 0; nt < 4; ++nt){
        u16x4 pv;
#pragma unroll
        for (int r = 0; r < 4; ++r){
          float e = __builtin_amdgcn_exp2f(tt[mt][nt][r] - mn);
          lsum += e;
          pv[r] = f2b(e);
        }
        const int c = nt * 2 + (quad >> 1);       // logical 16B chunk in row
        *(u16x4*)&sP[(q * 8 + (c ^ (q & 7))) * 8 + (quad & 1) * 4] = pv;
      }
      lsum += __shfl_xor(lsum, 16, 64);
      lsum += __shfl_xor(lsum, 32, 64);
      li[mt] = li[mt] * alpha + lsum;
#pragma unroll
      for (int dt = 0; dt < 8; ++dt){
        o[mt][dt][0] *= alpha; o[mt][dt][1] *= alpha;
        o[mt][dt][2] *= alpha; o[mt][dt][3] *= alpha;
      }
    }
    // no barrier: each wave reads back only its own sP rows (same-wave RAW)

    // O' += V^T·P^T : lane=q, (quad,reg)=d
#pragma unroll
    for (int kk = 0; kk < 2; ++kk){
      const int q0l = wave * 32 + lrow;
      bf16x8 yp0 = ldfrag(&sP[((q0l) * 8 + ((kk * 4 + quad) ^ (q0l & 7))) * 8]);
      const int q1l = q0l + 16;
      bf16x8 yp1 = ldfrag(&sP[((q1l) * 8 + ((kk * 4 + quad) ^ (q1l & 7))) * 8]);
#pragma unroll
      for (int dt = 0; dt < 8; ++dt){
        bf16x8 xv = ldfrag(&sV[((kk * 4 + quad) * 128 + dt * 16 + lrow) * 8]);
        o[0][dt] = __builtin_amdgcn_mfma_f32_16x16x32_bf16(xv, yp0, o[0][dt], 0, 0, 0);
        o[1][dt] = __builtin_amdgcn_mfma_f32_16x16x32_bf16(xv, yp1, o[1][dt], 0, 0, 0);
      }
    }
    __syncthreads();   // sP/sV reads done before next-iter staging
  }

  // epilogue: lane = q-row, regs = 4 consecutive d -> u16x4 stores
#pragma unroll
  for (int mt = 0; mt < 2; ++mt){
    const int t = qrow[mt];
    const float inv = 1.0f / li[mt];
    u16t* dst = Y + ((size_t)(b * 2048 + t)) * 4096 + h * 128 + quad * 4;
#pragma unroll
    for (int dt = 0; dt < 8; ++dt){
      u16x4 ov;
#pragma unroll
      for (int r = 0; r < 4; ++r) ov[r] = f2b(o[mt][dt][r] * inv);
      *(u16x4*)(dst + dt * 16) = ov;
    }
  }
}

// ---------------------------------------------------------------- launch
extern "C" void kernel_launch(void* const* d_in, const int* in_sizes, int n_in,
                              void* d_out, int out_size, void* d_ws, size_t ws_size,
                              hipStream_t stream)
{
  (void)in_sizes; (void)n_in; (void)out_size; (void)ws_size;
  const float* x    = (const float*)d_in[0];   // (2,2048,4096)
  const float* fc   = (const float*)d_in[1];   // (2048,64)
  const float* fs   = (const float*)d_in[2];   // (2048,64)
  const float* wqkv = (const float*)d_in[3];   // (6144,4096)
  const float* wo   = (const float*)d_in[4];   // (4096,4096)
  float* out = (float*)d_out;                  // (2,2048,4096) f32

  char* ws = (char*)d_ws;
  u16t* xb    = (u16t*)(ws);                    // 32 MiB (reused as yb after gemm1)
  u16t* wqkvb = (u16t*)(ws + 33554432);         // 48 MiB
  u16t* wob   = (u16t*)(ws + 83886080);         // 32 MiB
  u16t* qkvb  = (u16t*)(ws + 117440512);        // 48 MiB
  u16t* qr    = (u16t*)(ws + 167772160);        // 32 MiB
  u16t* kr    = (u16t*)(ws + 201326592);        //  8 MiB
  u16t* vt    = (u16t*)(ws + 209715200);        //  8 MiB  (total 208 MiB)
  u16t* yb    = xb;                             // alias: x dead after gemm1

  cvt_f32_bf16<<<4096, 256, 0, stream>>>(x,    xb,    16777216 / 4);
  cvt_f32_bf16<<<4096, 256, 0, stream>>>(wqkv, wqkvb, 25165824 / 4);
  cvt_f32_bf16<<<4096, 256, 0, stream>>>(wo,   wob,   16777216 / 4);
  gemm_bt<1><<<dim3(48, 32), 256, 0, stream>>>(xb, wqkvb, qkvb, 4096, 6144, 4096);
  rope_qk<<<4096, 256, 0, stream>>>(qkvb, fc, fs, qr, kr);
  vtrans<<<512, 256, 0, stream>>>(qkvb, vt);
  attn_fwd<<<dim3(64, 16), 256, 0, stream>>>(qr, kr, vt, yb);
  gemm_bt<0><<<dim3(32, 32), 256, 0, stream>>>(yb, wob, out, 4096, 4096, 4096);
}